// Round 14
// baseline (4895.063 us; speedup 1.0000x reference)
//
#include <hip/hip_runtime.h>
#include <math.h>

#define NB 8
#define NIN 16384
#define NP 2048
#define KNN 32
#define TOTPTS (NB * NP)   // 16384

#define NEG_INF (-__builtin_inff())
#define POS_INF (__builtin_inff())

// ---------------------------------------------------------------------------
// Packed fp32 ops (VOP3P): 2 round-to-nearest f32 ops per instruction.
// Bit-exact to __fadd_rn / __fmul_rn on each half. (No packed f32 min/max
// on gfx950 — r12 lesson.)
// ---------------------------------------------------------------------------
__device__ __forceinline__ float2 pk_add(float2 a, float2 b) {
  float2 d;
  asm("v_pk_add_f32 %0, %1, %2" : "=v"(d) : "v"(a), "v"(b));
  return d;
}
__device__ __forceinline__ float2 pk_mul(float2 a, float2 b) {
  float2 d;
  asm("v_pk_mul_f32 %0, %1, %2" : "=v"(d) : "v"(a), "v"(b));
  return d;
}

// ---------------------------------------------------------------------------
// DPP wave64 reductions; result valid in lane 63.
// ---------------------------------------------------------------------------
#define DPP_F(old, v, C, RM) \
  __int_as_float(__builtin_amdgcn_update_dpp(__float_as_int(old), __float_as_int(v), C, RM, 0xf, false))
#define DPP_I(old, v, C, RM) \
  __builtin_amdgcn_update_dpp(old, v, C, RM, 0xf, false)

__device__ __forceinline__ float wave_max_f(float v) {
  v = fmaxf(v, DPP_F(NEG_INF, v, 0x111, 0xf));
  v = fmaxf(v, DPP_F(NEG_INF, v, 0x112, 0xf));
  v = fmaxf(v, DPP_F(NEG_INF, v, 0x114, 0xf));
  v = fmaxf(v, DPP_F(NEG_INF, v, 0x118, 0xf));
  v = fmaxf(v, DPP_F(NEG_INF, v, 0x142, 0xa));
  v = fmaxf(v, DPP_F(NEG_INF, v, 0x143, 0xc));
  return v;
}
__device__ __forceinline__ int wave_min_i(int v) {
  v = min(v, DPP_I(0x7fffffff, v, 0x111, 0xf));
  v = min(v, DPP_I(0x7fffffff, v, 0x112, 0xf));
  v = min(v, DPP_I(0x7fffffff, v, 0x114, 0xf));
  v = min(v, DPP_I(0x7fffffff, v, 0x118, 0xf));
  v = min(v, DPP_I(0x7fffffff, v, 0x142, 0xa));
  v = min(v, DPP_I(0x7fffffff, v, 0x143, 0xc));
  return v;
}

__device__ __forceinline__ float readlane63f(float v) {
  return __int_as_float(__builtin_amdgcn_readlane(__float_as_int(v), 63));
}

// ---------------------------------------------------------------------------
// FPS: exact r9 structure (best measured: ~3430 us across r9/r13).
// ---------------------------------------------------------------------------
__global__ __launch_bounds__(1024) void fps_kernel(const float* __restrict__ x,
                                                   float* __restrict__ partial) {
  const int b = blockIdx.x;
  const int t = threadIdx.x;
  const int w = t >> 6, l = t & 63;
  const float* xb = x + (size_t)b * NIN * 3;
  float* pb = partial + (size_t)b * NP * 3;
  __shared__ unsigned long long skey[NP][2];
  __shared__ float4 swave[2][16];
  for (int i = t; i < NP; i += 1024) { skey[i][0] = 0ull; skey[i][1] = 0ull; }

  float2 px[8], py[8], pz[8], dd[8];
#pragma unroll
  for (int j = 0; j < 8; ++j) {
    const int i0 = (2 * j) * 1024 + t, i1 = (2 * j + 1) * 1024 + t;
    px[j] = make_float2(xb[3 * i0], xb[3 * i1]);
    py[j] = make_float2(xb[3 * i0 + 1], xb[3 * i1 + 1]);
    pz[j] = make_float2(xb[3 * i0 + 2], xb[3 * i1 + 2]);
  }
  const float qx0 = xb[0], qy0 = xb[1], qz0 = xb[2];
  if (t == 0) { pb[0] = qx0; pb[1] = qy0; pb[2] = qz0; }

  float bv = NEG_INF;
  int bi = 0;
  {
    const float2 nx2 = make_float2(-qx0, -qx0);
    const float2 ny2 = make_float2(-qy0, -qy0);
    const float2 nz2 = make_float2(-qz0, -qz0);
#pragma unroll
    for (int j = 0; j < 8; ++j) {
      float2 dx = pk_add(px[j], nx2), dy = pk_add(py[j], ny2), dz = pk_add(pz[j], nz2);
      float2 nd = pk_add(pk_add(pk_mul(dx, dx), pk_mul(dy, dy)), pk_mul(dz, dz));
      dd[j] = nd;
      if (nd.x > bv) { bv = nd.x; bi = (2 * j) * 1024 + t; }
      if (nd.y > bv) { bv = nd.y; bi = (2 * j + 1) * 1024 + t; }
    }
  }

  {
    const float wm = wave_max_f(bv);
    const float smaxw = readlane63f(wm);
    const int sel = (bv == smaxw) ? bi : 0x7fffffff;
    const int wiw = __builtin_amdgcn_readlane(wave_min_i(sel), 63);
    const float ax = xb[3 * wiw], ay = xb[3 * wiw + 1], az = xb[3 * wiw + 2];
    if (l == 63) {
      const unsigned long long key =
          ((unsigned long long)__float_as_uint(smaxw) << 32) | (unsigned int)(~wiw);
      atomicMax(&skey[1][w & 1], key);
    }
    if (l == 0) swave[1][w] = make_float4(ax, ay, az, 0.f);
  }
  __syncthreads();

  for (int it = 1; it < NP; ++it) {
    const unsigned long long k0 = skey[it][0], k1 = skey[it][1];
    const unsigned long long gk = (k0 > k1) ? k0 : k1;
    const int gbi = (int)(~(unsigned int)gk);
    const int wstar = (gbi >> 6) & 15;
    const float4 qc = swave[it & 1][wstar];
    const float nqx = qc.x, nqy = qc.y, nqz = qc.z;
    if (t == 0) { pb[3 * it] = nqx; pb[3 * it + 1] = nqy; pb[3 * it + 2] = nqz; }

    const float2 nx2 = make_float2(-nqx, -nqx);
    const float2 ny2 = make_float2(-nqy, -nqy);
    const float2 nz2 = make_float2(-nqz, -nqz);
    bv = NEG_INF;
    bi = 0;
#pragma unroll
    for (int j = 0; j < 8; ++j) {
      float2 dx = pk_add(px[j], nx2), dy = pk_add(py[j], ny2), dz = pk_add(pz[j], nz2);
      float2 nd = pk_add(pk_add(pk_mul(dx, dx), pk_mul(dy, dy)), pk_mul(dz, dz));
      const float a0 = fminf(dd[j].x, nd.x);
      dd[j].x = a0;
      if (a0 > bv) { bv = a0; bi = (2 * j) * 1024 + t; }
      const float a1 = fminf(dd[j].y, nd.y);
      dd[j].y = a1;
      if (a1 > bv) { bv = a1; bi = (2 * j + 1) * 1024 + t; }
    }

    if (it + 1 < NP) {
      const float wm = wave_max_f(bv);
      const float smaxw = readlane63f(wm);
      const int sel = (bv == smaxw) ? bi : 0x7fffffff;
      const int wiw = __builtin_amdgcn_readlane(wave_min_i(sel), 63);
      const float ax = xb[3 * wiw], ay = xb[3 * wiw + 1], az = xb[3 * wiw + 2];
      if (l == 63) {
        const unsigned long long key =
            ((unsigned long long)__float_as_uint(smaxw) << 32) | (unsigned int)(~wiw);
        atomicMax(&skey[it + 1][w & 1], key);
      }
      if (l == 0) swave[(it + 1) & 1][w] = make_float4(ax, ay, az, 0.f);
    }
    __syncthreads();
  }
}

// ---------------------------------------------------------------------------
// Fused layer-1 kNN (C=3): arithmetic bit-identical to dist_gemm<3>+select.
// ---------------------------------------------------------------------------
__global__ __launch_bounds__(1024) void knn3_kernel(const float* __restrict__ F,
                                                    int* __restrict__ idxg) {
  const int b = blockIdx.z;
  const int t = threadIdx.x;
  const int w = t >> 6, lane = t & 63;
  __shared__ float spx[NP], spy[NP], spz[NP], sxx[NP];
  const float* Fb = F + (size_t)b * NP * 3;
  for (int i = t; i < NP; i += 1024) {
    const float a0 = Fb[3 * i], a1 = Fb[3 * i + 1], a2 = Fb[3 * i + 2];
    spx[i] = a0; spy[i] = a1; spz[i] = a2;
    float s = __fadd_rn(0.f, __fmul_rn(a0, a0));
    s = __fadd_rn(s, __fmul_rn(a1, a1));
    s = __fadd_rn(s, __fmul_rn(a2, a2));
    sxx[i] = s;
  }
  __syncthreads();
  const int row = blockIdx.x * 16 + w;
  const float a0 = spx[row], a1 = spy[row], a2 = spz[row];
  const float xn = sxx[row];
  float v[32];
#pragma unroll
  for (int s = 0; s < 32; ++s) {
    const int m = s * 64 + lane;
    float acc = fmaf(a0, spx[m], 0.f);
    acc = fmaf(a1, spy[m], acc);
    acc = fmaf(a2, spz[m], acc);
    v[s] = __fsub_rn(__fsub_rn(2.0f * acc, xn), sxx[m]);
  }
  int* out = idxg + ((size_t)b * NP + row) * KNN;
  for (int tt = 0; tt < KNN; ++tt) {
    float bv = v[0];
    int bs = 0;
#pragma unroll
    for (int s = 1; s < 32; ++s) {
      if (v[s] > bv) { bv = v[s]; bs = s; }
    }
    int bi = bs * 64 + lane;
    const float vmax = readlane63f(wave_max_f(bv));
    const int sel = (bv == vmax) ? bi : 0x7fffffff;
    const int wbi = __builtin_amdgcn_readlane(wave_min_i(sel), 63);
    if (lane == 0) out[tt] = wbi;
    const bool own = (lane == (wbi & 63));
    const int cs = wbi >> 6;
#pragma unroll
    for (int s = 0; s < 32; ++s)
      if (own && s == cs) v[s] = NEG_INF;
  }
}

// ---------------------------------------------------------------------------
// Fused layer-2/3 kNN (C=64): replaces xx_kernel + dist_gemm<64> + select.
// 512 threads = 8 waves; wave w owns row blockIdx.x*8+w. 2048 points stream
// through LDS in 8 tiles of 256. Bit-exact vs the old path:
//  - distances: acc=0, fmaf ascending c (same as dist_gemm's inner loop on
//    identical staged copies), then (2*acc - xx_n) - xx_m with __fsub_rn;
//  - xx: __fadd_rn(__fmul_rn) ascending c from 0 (same as xx_kernel);
//  - v[s] mapping (s*64+lane) and top-32 loop copied verbatim from select.
// ---------------------------------------------------------------------------
__global__ __launch_bounds__(512) void knn64_kernel(const float* __restrict__ F,
                                                    int* __restrict__ idxg) {
  const int b = blockIdx.z;
  const int t = threadIdx.x;
  const int w = t >> 6, lane = t & 63;
  const int row = blockIdx.x * 8 + w;
  __shared__ float tile[256][65];
  __shared__ float sxx[256];
  __shared__ float srow[8][65];
  const float* Fb = F + (size_t)b * NP * 64;
  // stage this block's 8 rows
  for (int i = t; i < 8 * 64; i += 512) {
    const int r = i >> 6, c = i & 63;
    srow[r][c] = Fb[(size_t)(blockIdx.x * 8 + r) * 64 + c];
  }
  __syncthreads();
  float a[64];
#pragma unroll
  for (int c = 0; c < 64; ++c) a[c] = srow[w][c];
  float xn = 0.f;
#pragma unroll
  for (int c = 0; c < 64; ++c) xn = __fadd_rn(xn, __fmul_rn(a[c], a[c]));

  float v[32];
  for (int tt = 0; tt < 8; ++tt) {
    __syncthreads();  // previous tile fully consumed
    for (int i = t; i < 256 * 16; i += 512) {
      const int r = i >> 4, c4 = (i & 15) * 4;
      float4 q = *(const float4*)&Fb[(size_t)(tt * 256 + r) * 64 + c4];
      tile[r][c4] = q.x; tile[r][c4 + 1] = q.y;
      tile[r][c4 + 2] = q.z; tile[r][c4 + 3] = q.w;
    }
    __syncthreads();
    for (int i = t; i < 256; i += 512) {
      float s = 0.f;
      for (int c = 0; c < 64; ++c) s = __fadd_rn(s, __fmul_rn(tile[i][c], tile[i][c]));
      sxx[i] = s;
    }
    __syncthreads();
#pragma unroll
    for (int u = 0; u < 4; ++u) {
      const int ml = u * 64 + lane;
      float acc = 0.f;
#pragma unroll
      for (int c = 0; c < 64; ++c) acc = fmaf(a[c], tile[ml][c], acc);
      v[tt * 4 + u] = __fsub_rn(__fsub_rn(2.0f * acc, xn), sxx[ml]);
    }
  }

  int* out = idxg + ((size_t)b * NP + row) * KNN;
  for (int ttk = 0; ttk < KNN; ++ttk) {
    float bv = v[0];
    int bs = 0;
#pragma unroll
    for (int s = 1; s < 32; ++s) {
      if (v[s] > bv) { bv = v[s]; bs = s; }
    }
    int bi = bs * 64 + lane;
    const float vmax = readlane63f(wave_max_f(bv));
    const int sel = (bv == vmax) ? bi : 0x7fffffff;
    const int wbi = __builtin_amdgcn_readlane(wave_min_i(sel), 63);
    if (lane == 0) out[ttk] = wbi;
    const bool own = (lane == (wbi & 63));
    const int cs = wbi >> 6;
#pragma unroll
    for (int s = 0; s < 32; ++s)
      if (own && s == cs) v[s] = NEG_INF;
  }
}

// ---------------------------------------------------------------------------
// Layer-1 projections (C=3): per-point gather form (cheap at K=3).
// ---------------------------------------------------------------------------
template <int C, int DIM>
__global__ __launch_bounds__(256) void proj_kernel(
    const float* __restrict__ F, const float* __restrict__ pos,
    const float* __restrict__ Wq, const float* __restrict__ bq,
    const float* __restrict__ Wk, const float* __restrict__ bk,
    const float* __restrict__ Wv, const float* __restrict__ bv,
    const float* __restrict__ Wp, const float* __restrict__ bp,
    float* __restrict__ Uq, float* __restrict__ Uk, float* __restrict__ Uv,
    float* __restrict__ Uqc, float* __restrict__ Ukc, float* __restrict__ W6) {
  constexpr int PTS = 16;
  constexpr int GROUPS = 256 / DIM;
  constexpr int PPT = PTS / GROUPS;
  __shared__ float xs[PTS][C];
  __shared__ float ps[PTS][3];
  const int tid = threadIdx.x;
  const int base = blockIdx.x * PTS;
  for (int t = tid; t < PTS * C; t += 256) {
    int r = t / C;
    xs[r][t - r * C] = F[(size_t)(base + r) * C + (t - r * C)];
  }
  for (int t = tid; t < PTS * 3; t += 256) {
    int r = t / 3;
    ps[r][t - r * 3] = pos[(size_t)(base + r) * 3 + (t - r * 3)];
  }
  __syncthreads();
  const int g = tid / DIM;
  const int d = tid - g * DIM;
  float uq[PPT], uqd[PPT], uk[PPT], ukd[PPT], uv[PPT], uvd[PPT];
#pragma unroll
  for (int p = 0; p < PPT; ++p) { uq[p] = uqd[p] = uk[p] = ukd[p] = uv[p] = uvd[p] = 0.f; }
  const float* wqr = Wq + (size_t)d * (2 * C);
  const float* wkr = Wk + (size_t)d * (2 * C);
  const float* wvr = Wv + (size_t)d * (2 * C);
  for (int c = 0; c < C; ++c) {
    const float wq1 = wqr[c], wqd_ = wqr[C + c] - wq1;
    const float wk1 = wkr[c], wkd_ = wkr[C + c] - wk1;
    const float wv1 = wvr[c], wvd_ = wvr[C + c] - wv1;
#pragma unroll
    for (int p = 0; p < PPT; ++p) {
      const float xc = xs[g + p * GROUPS][c];
      uq[p] = fmaf(wq1, xc, uq[p]);
      uqd[p] = fmaf(wqd_, xc, uqd[p]);
      uk[p] = fmaf(wk1, xc, uk[p]);
      ukd[p] = fmaf(wkd_, xc, ukd[p]);
      uv[p] = fmaf(wv1, xc, uv[p]);
      uvd[p] = fmaf(wvd_, xc, uvd[p]);
    }
  }
  const float bqd = bq[d], bkd = bk[d], bvd = bv[d];
  const float wp0 = Wp[d * 3], wp1 = Wp[d * 3 + 1], wp2 = Wp[d * 3 + 2], bpd = bp[d];
#pragma unroll
  for (int p = 0; p < PPT; ++p) {
    const int lp = g + p * GROUPS;
    const size_t o = (size_t)(base + lp) * DIM + d;
    const float pd = wp0 * ps[lp][0] + wp1 * ps[lp][1] + wp2 * ps[lp][2] + bpd;
    Uq[o] = uq[p];
    Uqc[o] = uqd[p] + bqd;
    Uk[o] = uk[p];
    Ukc[o] = ukd[p] + bkd;
    Uv[o] = uv[p];
    W6[o] = uvd[p] + bvd + pd;
  }
}

// ---------------------------------------------------------------------------
// prep: Wcat[c][o] (c<64, o<6*DIM) = [Wq1|Wqd|Wk1|Wkd|Wv1|Wvd] transposed;
// bcat[o] = [0|bq|0|bk|0|bv].
// ---------------------------------------------------------------------------
template <int DIM>
__global__ void prep_kernel(const float* __restrict__ Wq, const float* __restrict__ bq,
                            const float* __restrict__ Wk, const float* __restrict__ bk,
                            const float* __restrict__ Wv, const float* __restrict__ bv,
                            float* __restrict__ Wcat, float* __restrict__ bcat) {
  const int o = blockIdx.x * 256 + threadIdx.x;
  constexpr int ND = 6 * DIM;
  if (o >= ND) return;
  const int blk = o / DIM, d = o % DIM;
  bcat[o] = (blk == 1) ? bq[d] : (blk == 3) ? bk[d] : (blk == 5) ? bv[d] : 0.f;
  const float* W = (blk < 2) ? Wq : (blk < 4) ? Wk : Wv;
  for (int c = 0; c < 64; ++c) {
    const float w1 = W[(size_t)d * 128 + c];
    const float w2 = W[(size_t)d * 128 + 64 + c];
    Wcat[(size_t)c * ND + o] = (blk & 1) ? (w2 - w1) : w1;
  }
}

// ---------------------------------------------------------------------------
// proj GEMM (layers 2/3, K=64): As[pt][k], Bs[k][col].
// pos-projection fused into the W6 (obuf==5) epilogue — no P buffer.
// ---------------------------------------------------------------------------
template <int DIM>
__global__ __launch_bounds__(256) void gemm_proj(
    const float* __restrict__ F, const float* __restrict__ Wcat,
    const float* __restrict__ bcat, const float* __restrict__ pos,
    const float* __restrict__ Wp, const float* __restrict__ bp,
    float* __restrict__ Uq, float* __restrict__ Uqc, float* __restrict__ Uk,
    float* __restrict__ Ukc, float* __restrict__ Uv, float* __restrict__ W6) {
  constexpr int ND = 6 * DIM;
  __shared__ float As[64][65];
  __shared__ float Bs[64][65];
  const int tid = threadIdx.x;
  const int r0blk = blockIdx.x * 64;
  const int n0 = blockIdx.y * 64;
  {
    const int r0 = tid >> 4, c4 = (tid & 15) * 4;
    for (int r = r0; r < 64; r += 16) {
      float4 a = *(const float4*)&F[(size_t)(r0blk + r) * 64 + c4];
      As[r][c4] = a.x; As[r][c4 + 1] = a.y; As[r][c4 + 2] = a.z; As[r][c4 + 3] = a.w;
      float4 bb = *(const float4*)&Wcat[(size_t)r * ND + n0 + c4];
      Bs[r][c4] = bb.x; Bs[r][c4 + 1] = bb.y; Bs[r][c4 + 2] = bb.z; Bs[r][c4 + 3] = bb.w;
    }
  }
  __syncthreads();
  const int tx = tid & 15, ty = tid >> 4;
  float acc[4][4] = {};
#pragma unroll 4
  for (int c = 0; c < 64; ++c) {
    float a[4], bb[4];
#pragma unroll
    for (int i = 0; i < 4; ++i) a[i] = As[ty * 4 + i][c];
#pragma unroll
    for (int j = 0; j < 4; ++j) bb[j] = Bs[c][tx * 4 + j];
#pragma unroll
    for (int i = 0; i < 4; ++i)
#pragma unroll
      for (int j = 0; j < 4; ++j) acc[i][j] = fmaf(a[i], bb[j], acc[i][j]);
  }
  const int obuf = n0 / DIM;
  const int oloc = n0 - obuf * DIM;
  float* outp = (obuf == 0) ? Uq : (obuf == 1) ? Uqc : (obuf == 2) ? Uk
              : (obuf == 3) ? Ukc : (obuf == 4) ? Uv : W6;
  const float b0 = bcat[n0 + tx * 4], b1 = bcat[n0 + tx * 4 + 1];
  const float b2 = bcat[n0 + tx * 4 + 2], b3 = bcat[n0 + tx * 4 + 3];
  float wpx[4], wpy[4], wpz[4], bpv[4];
  if (obuf == 5) {
#pragma unroll
    for (int j = 0; j < 4; ++j) {
      const int oc = oloc + tx * 4 + j;
      wpx[j] = Wp[oc * 3]; wpy[j] = Wp[oc * 3 + 1]; wpz[j] = Wp[oc * 3 + 2];
      bpv[j] = bp[oc];
    }
  }
#pragma unroll
  for (int i = 0; i < 4; ++i) {
    const int p = r0blk + ty * 4 + i;
    float4 r = make_float4(acc[i][0] + b0, acc[i][1] + b1, acc[i][2] + b2, acc[i][3] + b3);
    if (obuf == 5) {
      const float q0 = pos[(size_t)p * 3], q1 = pos[(size_t)p * 3 + 1], q2 = pos[(size_t)p * 3 + 2];
      r.x += wpx[0] * q0 + wpy[0] * q1 + wpz[0] * q2 + bpv[0];
      r.y += wpx[1] * q0 + wpy[1] * q1 + wpz[1] * q2 + bpv[1];
      r.z += wpx[2] * q0 + wpy[2] * q1 + wpz[2] * q2 + bpv[2];
      r.w += wpx[3] * q0 + wpy[3] * q1 + wpz[3] * q2 + bpv[3];
    }
    *(float4*)&outp[(size_t)p * DIM + oloc + tx * 4] = r;
  }
}

// ---------------------------------------------------------------------------
// Attention. QK: all 64 lanes (lane = k + 32*dhalf), one shfl_xor(32) combine.
// ---------------------------------------------------------------------------
template <int DIM>
__global__ __launch_bounds__(256) void attn_kernel(
    const float* __restrict__ Uq, const float* __restrict__ Uk, const float* __restrict__ Uv,
    const float* __restrict__ Uqc, const float* __restrict__ Ukc, const float* __restrict__ W6g,
    const int* __restrict__ idxg, float* __restrict__ outF) {
  const int w = threadIdx.x >> 6, lane = threadIdx.x & 63;
  const int pt = blockIdx.x * 4 + w;
  const int b = pt >> 11;
  __shared__ int sidx[4][KNN];
  __shared__ float sqc[4][DIM], skc[4][DIM], sw6[4][DIM];
  __shared__ float sattn[4][KNN];
  const size_t rowo = (size_t)pt * DIM;
  if (lane < KNN) sidx[w][lane] = idxg[(size_t)pt * KNN + lane];
  for (int d = lane; d < DIM; d += 64) {
    sqc[w][d] = Uqc[rowo + d];
    skc[w][d] = Ukc[rowo + d];
    sw6[w][d] = W6g[rowo + d];
  }
  __syncthreads();
  {
    const int kk = lane & 31;
    const int h = lane >> 5;
    const int ik = sidx[w][kk];
    const float* qr = Uq + (size_t)(b * NP + ik) * DIM;
    const float* kr = Uk + (size_t)(b * NP + ik) * DIM;
    float lg = 0.f;
    const int d0 = h * (DIM / 2), d1 = d0 + DIM / 2;
    for (int d = d0; d < d1; d += 4) {
      float4 qa = *(const float4*)(qr + d);
      float4 ka = *(const float4*)(kr + d);
      float4 qc = *(const float4*)(&sqc[w][d]);
      float4 kc = *(const float4*)(&skc[w][d]);
      lg += (qa.x + qc.x) * (ka.x + kc.x);
      lg += (qa.y + qc.y) * (ka.y + kc.y);
      lg += (qa.z + qc.z) * (ka.z + kc.z);
      lg += (qa.w + qc.w) * (ka.w + kc.w);
    }
    lg += __shfl_xor(lg, 32);
    lg *= (DIM == 64) ? 0.125f : 0.08838834764831845f;  // 1/sqrt(DIM)
    float m = lg;
#pragma unroll
    for (int off = 16; off; off >>= 1) m = fmaxf(m, __shfl_xor(m, off));
    float e = expf(lg - m);
    float s = e;
#pragma unroll
    for (int off = 16; off; off >>= 1) s += __shfl_xor(s, off);
    if (lane < KNN) sattn[w][lane] = e / s;
  }
  __syncthreads();
  float acc[DIM / 64];
#pragma unroll
  for (int q = 0; q < DIM / 64; ++q) acc[q] = 0.f;
  for (int k = 0; k < KNN; ++k) {
    const int ik = sidx[w][k];
    const float a = sattn[w][k];
    const float* vr = Uv + (size_t)(b * NP + ik) * DIM;
#pragma unroll
    for (int q = 0; q < DIM / 64; ++q) {
      const int d = q * 64 + lane;
      acc[q] = fmaf(a, vr[d] + sw6[w][d], acc[q]);
    }
  }
#pragma unroll
  for (int q = 0; q < DIM / 64; ++q) outF[rowo + q * 64 + lane] = acc[q];
}

// ---------------------------------------------------------------------------
// Pooling, two stages for HBM parallelism.
// ---------------------------------------------------------------------------
#define PCHUNKS 16
__global__ __launch_bounds__(256) void pool1_kernel(const float* __restrict__ x1,
                                                    const float* __restrict__ x2,
                                                    const float* __restrict__ x3,
                                                    float* __restrict__ pmax,
                                                    float* __restrict__ psum) {
  const int b = blockIdx.x, ch = blockIdx.y, c = threadIdx.x;
  const float* src;
  int dim, cl;
  if (c < 64) {
    src = x1 + (size_t)b * NP * 64; dim = 64; cl = c;
  } else if (c < 128) {
    src = x2 + (size_t)b * NP * 64; dim = 64; cl = c - 64;
  } else {
    src = x3 + (size_t)b * NP * 128; dim = 128; cl = c - 128;
  }
  const int n0 = ch * (NP / PCHUNKS), n1 = n0 + NP / PCHUNKS;
  float mx = NEG_INF, sm = 0.f;
#pragma unroll 8
  for (int n = n0; n < n1; ++n) {
    float v = src[(size_t)n * dim + cl];
    mx = fmaxf(mx, v);
    sm += v;
  }
  const size_t o = ((size_t)b * PCHUNKS + ch) * 256 + c;
  pmax[o] = mx;
  psum[o] = sm;
}

__global__ __launch_bounds__(256) void pool2_kernel(const float* __restrict__ pmax,
                                                    const float* __restrict__ psum,
                                                    float* __restrict__ out) {
  const int b = blockIdx.x, c = threadIdx.x;
  float mx = NEG_INF, sm = 0.f;
#pragma unroll
  for (int ch = 0; ch < PCHUNKS; ++ch) {
    const size_t o = ((size_t)b * PCHUNKS + ch) * 256 + c;
    mx = fmaxf(mx, pmax[o]);
    sm += psum[o];
  }
  out[b * 512 + c] = mx;
  out[b * 512 + 256 + c] = sm * (1.0f / 2048.0f);
}

// ---------------------------------------------------------------------------
extern "C" void kernel_launch(void* const* d_in, const int* in_sizes, int n_in,
                              void* d_out, int out_size, void* d_ws, size_t ws_size,
                              hipStream_t stream) {
  const float* x = (const float*)d_in[0];
  const float* W[24];
  for (int i = 0; i < 24; ++i) W[i] = (const float*)d_in[1 + i];

  float* ws = (float*)d_ws;
  size_t off = 0;
  float* partial = ws + off; off += (size_t)NB * NP * 3;
  int* idxb = (int*)(ws + off); off += (size_t)TOTPTS * KNN;
  float* x1 = ws + off; off += (size_t)TOTPTS * 64;
  float* x2 = ws + off; off += (size_t)TOTPTS * 64;
  float* x3 = ws + off; off += (size_t)TOTPTS * 128;
  float* Uq = ws + off;  off += (size_t)TOTPTS * 128;
  float* Uk = ws + off;  off += (size_t)TOTPTS * 128;
  float* Uv = ws + off;  off += (size_t)TOTPTS * 128;
  float* Uqc = ws + off; off += (size_t)TOTPTS * 128;
  float* Ukc = ws + off; off += (size_t)TOTPTS * 128;
  float* W6 = ws + off;  off += (size_t)TOTPTS * 128;
  float* Wcat = ws + off; off += (size_t)64 * 768;
  float* bcat = ws + off; off += 768;
  float* pmax = ws + off; off += (size_t)NB * PCHUNKS * 256;
  float* psum = ws + off; off += (size_t)NB * PCHUNKS * 256;
  if (ws_size < off * sizeof(float)) return;

  fps_kernel<<<NB, 1024, 0, stream>>>(x, partial);

  // -------- layer 1 (C=3, DIM=64): fused kNN
  knn3_kernel<<<dim3(NP / 16, 1, NB), 1024, 0, stream>>>(partial, idxb);
  proj_kernel<3, 64><<<TOTPTS / 16, 256, 0, stream>>>(
      partial, partial, W[0], W[1], W[2], W[3], W[4], W[5], W[6], W[7],
      Uq, Uk, Uv, Uqc, Ukc, W6);
  attn_kernel<64><<<TOTPTS / 4, 256, 0, stream>>>(Uq, Uk, Uv, Uqc, Ukc, W6, idxb, x1);

  // -------- layer 2 (C=64, DIM=64): fused kNN (no D matrix)
  knn64_kernel<<<dim3(NP / 8, 1, NB), 512, 0, stream>>>(x1, idxb);
  prep_kernel<64><<<2, 256, 0, stream>>>(W[8], W[9], W[10], W[11], W[12], W[13], Wcat, bcat);
  gemm_proj<64><<<dim3(TOTPTS / 64, 6), 256, 0, stream>>>(
      x1, Wcat, bcat, partial, W[14], W[15], Uq, Uqc, Uk, Ukc, Uv, W6);
  attn_kernel<64><<<TOTPTS / 4, 256, 0, stream>>>(Uq, Uk, Uv, Uqc, Ukc, W6, idxb, x2);

  // -------- layer 3 (C=64, DIM=128): fused kNN
  knn64_kernel<<<dim3(NP / 8, 1, NB), 512, 0, stream>>>(x2, idxb);
  prep_kernel<128><<<3, 256, 0, stream>>>(W[16], W[17], W[18], W[19], W[20], W[21], Wcat, bcat);
  gemm_proj<128><<<dim3(TOTPTS / 64, 12), 256, 0, stream>>>(
      x2, Wcat, bcat, partial, W[22], W[23], Uq, Uqc, Uk, Ukc, Uv, W6);
  attn_kernel<128><<<TOTPTS / 4, 256, 0, stream>>>(Uq, Uk, Uv, Uqc, Ukc, W6, idxb, x3);

  pool1_kernel<<<dim3(NB, PCHUNKS), 256, 0, stream>>>(x1, x2, x3, pmax, psum);
  pool2_kernel<<<NB, 256, 0, stream>>>(pmax, psum, (float*)d_out);
}

// Round 15
// 4587.082 us; speedup vs baseline: 1.0671x; 1.0671x over previous
//
#include <hip/hip_runtime.h>
#include <math.h>

#define NB 8
#define NIN 16384
#define NP 2048
#define KNN 32
#define TOTPTS (NB * NP)   // 16384

#define NEG_INF (-__builtin_inff())
#define POS_INF (__builtin_inff())

// ---------------------------------------------------------------------------
// Packed fp32 ops (VOP3P): 2 round-to-nearest f32 ops per instruction.
// Bit-exact to __fadd_rn / __fmul_rn on each half. (No packed f32 min/max
// on gfx950 — r12 lesson.)
// ---------------------------------------------------------------------------
__device__ __forceinline__ float2 pk_add(float2 a, float2 b) {
  float2 d;
  asm("v_pk_add_f32 %0, %1, %2" : "=v"(d) : "v"(a), "v"(b));
  return d;
}
__device__ __forceinline__ float2 pk_mul(float2 a, float2 b) {
  float2 d;
  asm("v_pk_mul_f32 %0, %1, %2" : "=v"(d) : "v"(a), "v"(b));
  return d;
}

// ---------------------------------------------------------------------------
// DPP wave64 reductions; result valid in lane 63.
// ---------------------------------------------------------------------------
#define DPP_F(old, v, C, RM) \
  __int_as_float(__builtin_amdgcn_update_dpp(__float_as_int(old), __float_as_int(v), C, RM, 0xf, false))
#define DPP_I(old, v, C, RM) \
  __builtin_amdgcn_update_dpp(old, v, C, RM, 0xf, false)

__device__ __forceinline__ float wave_max_f(float v) {
  v = fmaxf(v, DPP_F(NEG_INF, v, 0x111, 0xf));
  v = fmaxf(v, DPP_F(NEG_INF, v, 0x112, 0xf));
  v = fmaxf(v, DPP_F(NEG_INF, v, 0x114, 0xf));
  v = fmaxf(v, DPP_F(NEG_INF, v, 0x118, 0xf));
  v = fmaxf(v, DPP_F(NEG_INF, v, 0x142, 0xa));
  v = fmaxf(v, DPP_F(NEG_INF, v, 0x143, 0xc));
  return v;
}
__device__ __forceinline__ int wave_min_i(int v) {
  v = min(v, DPP_I(0x7fffffff, v, 0x111, 0xf));
  v = min(v, DPP_I(0x7fffffff, v, 0x112, 0xf));
  v = min(v, DPP_I(0x7fffffff, v, 0x114, 0xf));
  v = min(v, DPP_I(0x7fffffff, v, 0x118, 0xf));
  v = min(v, DPP_I(0x7fffffff, v, 0x142, 0xa));
  v = min(v, DPP_I(0x7fffffff, v, 0x143, 0xc));
  return v;
}

__device__ __forceinline__ float readlane63f(float v) {
  return __int_as_float(__builtin_amdgcn_readlane(__float_as_int(v), 63));
}

// ---------------------------------------------------------------------------
// FPS: exact r9 structure (best measured: ~3430 us across r9/r13/r14).
// ---------------------------------------------------------------------------
__global__ __launch_bounds__(1024) void fps_kernel(const float* __restrict__ x,
                                                   float* __restrict__ partial) {
  const int b = blockIdx.x;
  const int t = threadIdx.x;
  const int w = t >> 6, l = t & 63;
  const float* xb = x + (size_t)b * NIN * 3;
  float* pb = partial + (size_t)b * NP * 3;
  __shared__ unsigned long long skey[NP][2];
  __shared__ float4 swave[2][16];
  for (int i = t; i < NP; i += 1024) { skey[i][0] = 0ull; skey[i][1] = 0ull; }

  float2 px[8], py[8], pz[8], dd[8];
#pragma unroll
  for (int j = 0; j < 8; ++j) {
    const int i0 = (2 * j) * 1024 + t, i1 = (2 * j + 1) * 1024 + t;
    px[j] = make_float2(xb[3 * i0], xb[3 * i1]);
    py[j] = make_float2(xb[3 * i0 + 1], xb[3 * i1 + 1]);
    pz[j] = make_float2(xb[3 * i0 + 2], xb[3 * i1 + 2]);
  }
  const float qx0 = xb[0], qy0 = xb[1], qz0 = xb[2];
  if (t == 0) { pb[0] = qx0; pb[1] = qy0; pb[2] = qz0; }

  float bv = NEG_INF;
  int bi = 0;
  {
    const float2 nx2 = make_float2(-qx0, -qx0);
    const float2 ny2 = make_float2(-qy0, -qy0);
    const float2 nz2 = make_float2(-qz0, -qz0);
#pragma unroll
    for (int j = 0; j < 8; ++j) {
      float2 dx = pk_add(px[j], nx2), dy = pk_add(py[j], ny2), dz = pk_add(pz[j], nz2);
      float2 nd = pk_add(pk_add(pk_mul(dx, dx), pk_mul(dy, dy)), pk_mul(dz, dz));
      dd[j] = nd;
      if (nd.x > bv) { bv = nd.x; bi = (2 * j) * 1024 + t; }
      if (nd.y > bv) { bv = nd.y; bi = (2 * j + 1) * 1024 + t; }
    }
  }

  {
    const float wm = wave_max_f(bv);
    const float smaxw = readlane63f(wm);
    const int sel = (bv == smaxw) ? bi : 0x7fffffff;
    const int wiw = __builtin_amdgcn_readlane(wave_min_i(sel), 63);
    const float ax = xb[3 * wiw], ay = xb[3 * wiw + 1], az = xb[3 * wiw + 2];
    if (l == 63) {
      const unsigned long long key =
          ((unsigned long long)__float_as_uint(smaxw) << 32) | (unsigned int)(~wiw);
      atomicMax(&skey[1][w & 1], key);
    }
    if (l == 0) swave[1][w] = make_float4(ax, ay, az, 0.f);
  }
  __syncthreads();

  for (int it = 1; it < NP; ++it) {
    const unsigned long long k0 = skey[it][0], k1 = skey[it][1];
    const unsigned long long gk = (k0 > k1) ? k0 : k1;
    const int gbi = (int)(~(unsigned int)gk);
    const int wstar = (gbi >> 6) & 15;
    const float4 qc = swave[it & 1][wstar];
    const float nqx = qc.x, nqy = qc.y, nqz = qc.z;
    if (t == 0) { pb[3 * it] = nqx; pb[3 * it + 1] = nqy; pb[3 * it + 2] = nqz; }

    const float2 nx2 = make_float2(-nqx, -nqx);
    const float2 ny2 = make_float2(-nqy, -nqy);
    const float2 nz2 = make_float2(-nqz, -nqz);
    bv = NEG_INF;
    bi = 0;
#pragma unroll
    for (int j = 0; j < 8; ++j) {
      float2 dx = pk_add(px[j], nx2), dy = pk_add(py[j], ny2), dz = pk_add(pz[j], nz2);
      float2 nd = pk_add(pk_add(pk_mul(dx, dx), pk_mul(dy, dy)), pk_mul(dz, dz));
      const float a0 = fminf(dd[j].x, nd.x);
      dd[j].x = a0;
      if (a0 > bv) { bv = a0; bi = (2 * j) * 1024 + t; }
      const float a1 = fminf(dd[j].y, nd.y);
      dd[j].y = a1;
      if (a1 > bv) { bv = a1; bi = (2 * j + 1) * 1024 + t; }
    }

    if (it + 1 < NP) {
      const float wm = wave_max_f(bv);
      const float smaxw = readlane63f(wm);
      const int sel = (bv == smaxw) ? bi : 0x7fffffff;
      const int wiw = __builtin_amdgcn_readlane(wave_min_i(sel), 63);
      const float ax = xb[3 * wiw], ay = xb[3 * wiw + 1], az = xb[3 * wiw + 2];
      if (l == 63) {
        const unsigned long long key =
            ((unsigned long long)__float_as_uint(smaxw) << 32) | (unsigned int)(~wiw);
        atomicMax(&skey[it + 1][w & 1], key);
      }
      if (l == 0) swave[(it + 1) & 1][w] = make_float4(ax, ay, az, 0.f);
    }
    __syncthreads();
  }
}

// ---------------------------------------------------------------------------
// Fused layer-1 kNN (C=3): arithmetic bit-identical to dist_gemm<3>+select.
// ---------------------------------------------------------------------------
__global__ __launch_bounds__(1024) void knn3_kernel(const float* __restrict__ F,
                                                    int* __restrict__ idxg) {
  const int b = blockIdx.z;
  const int t = threadIdx.x;
  const int w = t >> 6, lane = t & 63;
  __shared__ float spx[NP], spy[NP], spz[NP], sxx[NP];
  const float* Fb = F + (size_t)b * NP * 3;
  for (int i = t; i < NP; i += 1024) {
    const float a0 = Fb[3 * i], a1 = Fb[3 * i + 1], a2 = Fb[3 * i + 2];
    spx[i] = a0; spy[i] = a1; spz[i] = a2;
    float s = __fadd_rn(0.f, __fmul_rn(a0, a0));
    s = __fadd_rn(s, __fmul_rn(a1, a1));
    s = __fadd_rn(s, __fmul_rn(a2, a2));
    sxx[i] = s;
  }
  __syncthreads();
  const int row = blockIdx.x * 16 + w;
  const float a0 = spx[row], a1 = spy[row], a2 = spz[row];
  const float xn = sxx[row];
  float v[32];
#pragma unroll
  for (int s = 0; s < 32; ++s) {
    const int m = s * 64 + lane;
    float acc = fmaf(a0, spx[m], 0.f);
    acc = fmaf(a1, spy[m], acc);
    acc = fmaf(a2, spz[m], acc);
    v[s] = __fsub_rn(__fsub_rn(2.0f * acc, xn), sxx[m]);
  }
  int* out = idxg + ((size_t)b * NP + row) * KNN;
  for (int tt = 0; tt < KNN; ++tt) {
    float bv = v[0];
    int bs = 0;
#pragma unroll
    for (int s = 1; s < 32; ++s) {
      if (v[s] > bv) { bv = v[s]; bs = s; }
    }
    int bi = bs * 64 + lane;
    const float vmax = readlane63f(wave_max_f(bv));
    const int sel = (bv == vmax) ? bi : 0x7fffffff;
    const int wbi = __builtin_amdgcn_readlane(wave_min_i(sel), 63);
    if (lane == 0) out[tt] = wbi;
    const bool own = (lane == (wbi & 63));
    const int cs = wbi >> 6;
#pragma unroll
    for (int s = 0; s < 32; ++s)
      if (own && s == cs) v[s] = NEG_INF;
  }
}

// ---------------------------------------------------------------------------
// Fused layer-2/3 kNN (C=64), TRANSPOSED tile (r15 fix for r14's 8.4M LDS
// bank conflicts): tile[c][r] with row stride 257 -> the distance loop reads
// tile[c][u*64+lane]: consecutive lanes = consecutive addresses, conflict-
// free b32 at full LDS rate. Arithmetic bit-identical to xx+dist_gemm+select:
//  - xx: __fadd_rn(__fmul_rn) ascending c from 0;
//  - dist: acc=0, fmaf ascending c, (2*acc - xx_n) - xx_m rn;
//  - v[s]=D[row][s*64+lane] mapping and top-32 loop verbatim from select.
// ---------------------------------------------------------------------------
#define KPAD 257
__global__ __launch_bounds__(512) void knn64_kernel(const float* __restrict__ F,
                                                    int* __restrict__ idxg) {
  const int b = blockIdx.z;
  const int t = threadIdx.x;
  const int w = t >> 6, lane = t & 63;
  const int row = blockIdx.x * 8 + w;
  __shared__ float tile[64][KPAD];   // [c][r], 257-stride -> conflict-free
  __shared__ float sxx[256];
  __shared__ float srow[8][65];
  const float* Fb = F + (size_t)b * NP * 64;
  // stage this block's 8 rows
  for (int i = t; i < 8 * 64; i += 512) {
    const int r = i >> 6, c = i & 63;
    srow[r][c] = Fb[(size_t)(blockIdx.x * 8 + r) * 64 + c];
  }
  __syncthreads();
  float a[64];
#pragma unroll
  for (int c = 0; c < 64; ++c) a[c] = srow[w][c];
  float xn = 0.f;
#pragma unroll
  for (int c = 0; c < 64; ++c) xn = __fadd_rn(xn, __fmul_rn(a[c], a[c]));

  float v[32];
  for (int tt = 0; tt < 8; ++tt) {
    __syncthreads();  // previous tile fully consumed
    for (int i = t; i < 256 * 16; i += 512) {
      const int r = i >> 4, c4 = (i & 15) * 4;
      float4 q = *(const float4*)&Fb[(size_t)(tt * 256 + r) * 64 + c4];
      tile[c4][r] = q.x; tile[c4 + 1][r] = q.y;
      tile[c4 + 2][r] = q.z; tile[c4 + 3][r] = q.w;
    }
    __syncthreads();
    for (int i = t; i < 256; i += 512) {
      float s = 0.f;
      for (int c = 0; c < 64; ++c) s = __fadd_rn(s, __fmul_rn(tile[c][i], tile[c][i]));
      sxx[i] = s;
    }
    __syncthreads();
#pragma unroll
    for (int u = 0; u < 4; ++u) {
      const int ml = u * 64 + lane;
      float acc = 0.f;
#pragma unroll
      for (int c = 0; c < 64; ++c) acc = fmaf(a[c], tile[c][ml], acc);
      v[tt * 4 + u] = __fsub_rn(__fsub_rn(2.0f * acc, xn), sxx[ml]);
    }
  }

  int* out = idxg + ((size_t)b * NP + row) * KNN;
  for (int ttk = 0; ttk < KNN; ++ttk) {
    float bv = v[0];
    int bs = 0;
#pragma unroll
    for (int s = 1; s < 32; ++s) {
      if (v[s] > bv) { bv = v[s]; bs = s; }
    }
    int bi = bs * 64 + lane;
    const float vmax = readlane63f(wave_max_f(bv));
    const int sel = (bv == vmax) ? bi : 0x7fffffff;
    const int wbi = __builtin_amdgcn_readlane(wave_min_i(sel), 63);
    if (lane == 0) out[ttk] = wbi;
    const bool own = (lane == (wbi & 63));
    const int cs = wbi >> 6;
#pragma unroll
    for (int s = 0; s < 32; ++s)
      if (own && s == cs) v[s] = NEG_INF;
  }
}

// ---------------------------------------------------------------------------
// Layer-1 projections (C=3): per-point gather form (cheap at K=3).
// ---------------------------------------------------------------------------
template <int C, int DIM>
__global__ __launch_bounds__(256) void proj_kernel(
    const float* __restrict__ F, const float* __restrict__ pos,
    const float* __restrict__ Wq, const float* __restrict__ bq,
    const float* __restrict__ Wk, const float* __restrict__ bk,
    const float* __restrict__ Wv, const float* __restrict__ bv,
    const float* __restrict__ Wp, const float* __restrict__ bp,
    float* __restrict__ Uq, float* __restrict__ Uk, float* __restrict__ Uv,
    float* __restrict__ Uqc, float* __restrict__ Ukc, float* __restrict__ W6) {
  constexpr int PTS = 16;
  constexpr int GROUPS = 256 / DIM;
  constexpr int PPT = PTS / GROUPS;
  __shared__ float xs[PTS][C];
  __shared__ float ps[PTS][3];
  const int tid = threadIdx.x;
  const int base = blockIdx.x * PTS;
  for (int t = tid; t < PTS * C; t += 256) {
    int r = t / C;
    xs[r][t - r * C] = F[(size_t)(base + r) * C + (t - r * C)];
  }
  for (int t = tid; t < PTS * 3; t += 256) {
    int r = t / 3;
    ps[r][t - r * 3] = pos[(size_t)(base + r) * 3 + (t - r * 3)];
  }
  __syncthreads();
  const int g = tid / DIM;
  const int d = tid - g * DIM;
  float uq[PPT], uqd[PPT], uk[PPT], ukd[PPT], uv[PPT], uvd[PPT];
#pragma unroll
  for (int p = 0; p < PPT; ++p) { uq[p] = uqd[p] = uk[p] = ukd[p] = uv[p] = uvd[p] = 0.f; }
  const float* wqr = Wq + (size_t)d * (2 * C);
  const float* wkr = Wk + (size_t)d * (2 * C);
  const float* wvr = Wv + (size_t)d * (2 * C);
  for (int c = 0; c < C; ++c) {
    const float wq1 = wqr[c], wqd_ = wqr[C + c] - wq1;
    const float wk1 = wkr[c], wkd_ = wkr[C + c] - wk1;
    const float wv1 = wvr[c], wvd_ = wvr[C + c] - wv1;
#pragma unroll
    for (int p = 0; p < PPT; ++p) {
      const float xc = xs[g + p * GROUPS][c];
      uq[p] = fmaf(wq1, xc, uq[p]);
      uqd[p] = fmaf(wqd_, xc, uqd[p]);
      uk[p] = fmaf(wk1, xc, uk[p]);
      ukd[p] = fmaf(wkd_, xc, ukd[p]);
      uv[p] = fmaf(wv1, xc, uv[p]);
      uvd[p] = fmaf(wvd_, xc, uvd[p]);
    }
  }
  const float bqd = bq[d], bkd = bk[d], bvd = bv[d];
  const float wp0 = Wp[d * 3], wp1 = Wp[d * 3 + 1], wp2 = Wp[d * 3 + 2], bpd = bp[d];
#pragma unroll
  for (int p = 0; p < PPT; ++p) {
    const int lp = g + p * GROUPS;
    const size_t o = (size_t)(base + lp) * DIM + d;
    const float pd = wp0 * ps[lp][0] + wp1 * ps[lp][1] + wp2 * ps[lp][2] + bpd;
    Uq[o] = uq[p];
    Uqc[o] = uqd[p] + bqd;
    Uk[o] = uk[p];
    Ukc[o] = ukd[p] + bkd;
    Uv[o] = uv[p];
    W6[o] = uvd[p] + bvd + pd;
  }
}

// ---------------------------------------------------------------------------
// prep: Wcat[c][o] (c<64, o<6*DIM) = [Wq1|Wqd|Wk1|Wkd|Wv1|Wvd] transposed;
// bcat[o] = [0|bq|0|bk|0|bv].
// ---------------------------------------------------------------------------
template <int DIM>
__global__ void prep_kernel(const float* __restrict__ Wq, const float* __restrict__ bq,
                            const float* __restrict__ Wk, const float* __restrict__ bk,
                            const float* __restrict__ Wv, const float* __restrict__ bv,
                            float* __restrict__ Wcat, float* __restrict__ bcat) {
  const int o = blockIdx.x * 256 + threadIdx.x;
  constexpr int ND = 6 * DIM;
  if (o >= ND) return;
  const int blk = o / DIM, d = o % DIM;
  bcat[o] = (blk == 1) ? bq[d] : (blk == 3) ? bk[d] : (blk == 5) ? bv[d] : 0.f;
  const float* W = (blk < 2) ? Wq : (blk < 4) ? Wk : Wv;
  for (int c = 0; c < 64; ++c) {
    const float w1 = W[(size_t)d * 128 + c];
    const float w2 = W[(size_t)d * 128 + 64 + c];
    Wcat[(size_t)c * ND + o] = (blk & 1) ? (w2 - w1) : w1;
  }
}

// ---------------------------------------------------------------------------
// proj GEMM (layers 2/3, K=64): As[pt][k], Bs[k][col].
// pos-projection fused into the W6 (obuf==5) epilogue — no P buffer.
// ---------------------------------------------------------------------------
template <int DIM>
__global__ __launch_bounds__(256) void gemm_proj(
    const float* __restrict__ F, const float* __restrict__ Wcat,
    const float* __restrict__ bcat, const float* __restrict__ pos,
    const float* __restrict__ Wp, const float* __restrict__ bp,
    float* __restrict__ Uq, float* __restrict__ Uqc, float* __restrict__ Uk,
    float* __restrict__ Ukc, float* __restrict__ Uv, float* __restrict__ W6) {
  constexpr int ND = 6 * DIM;
  __shared__ float As[64][65];
  __shared__ float Bs[64][65];
  const int tid = threadIdx.x;
  const int r0blk = blockIdx.x * 64;
  const int n0 = blockIdx.y * 64;
  {
    const int r0 = tid >> 4, c4 = (tid & 15) * 4;
    for (int r = r0; r < 64; r += 16) {
      float4 a = *(const float4*)&F[(size_t)(r0blk + r) * 64 + c4];
      As[r][c4] = a.x; As[r][c4 + 1] = a.y; As[r][c4 + 2] = a.z; As[r][c4 + 3] = a.w;
      float4 bb = *(const float4*)&Wcat[(size_t)r * ND + n0 + c4];
      Bs[r][c4] = bb.x; Bs[r][c4 + 1] = bb.y; Bs[r][c4 + 2] = bb.z; Bs[r][c4 + 3] = bb.w;
    }
  }
  __syncthreads();
  const int tx = tid & 15, ty = tid >> 4;
  float acc[4][4] = {};
#pragma unroll 4
  for (int c = 0; c < 64; ++c) {
    float a[4], bb[4];
#pragma unroll
    for (int i = 0; i < 4; ++i) a[i] = As[ty * 4 + i][c];
#pragma unroll
    for (int j = 0; j < 4; ++j) bb[j] = Bs[c][tx * 4 + j];
#pragma unroll
    for (int i = 0; i < 4; ++i)
#pragma unroll
      for (int j = 0; j < 4; ++j) acc[i][j] = fmaf(a[i], bb[j], acc[i][j]);
  }
  const int obuf = n0 / DIM;
  const int oloc = n0 - obuf * DIM;
  float* outp = (obuf == 0) ? Uq : (obuf == 1) ? Uqc : (obuf == 2) ? Uk
              : (obuf == 3) ? Ukc : (obuf == 4) ? Uv : W6;
  const float b0 = bcat[n0 + tx * 4], b1 = bcat[n0 + tx * 4 + 1];
  const float b2 = bcat[n0 + tx * 4 + 2], b3 = bcat[n0 + tx * 4 + 3];
  float wpx[4], wpy[4], wpz[4], bpv[4];
  if (obuf == 5) {
#pragma unroll
    for (int j = 0; j < 4; ++j) {
      const int oc = oloc + tx * 4 + j;
      wpx[j] = Wp[oc * 3]; wpy[j] = Wp[oc * 3 + 1]; wpz[j] = Wp[oc * 3 + 2];
      bpv[j] = bp[oc];
    }
  }
#pragma unroll
  for (int i = 0; i < 4; ++i) {
    const int p = r0blk + ty * 4 + i;
    float4 r = make_float4(acc[i][0] + b0, acc[i][1] + b1, acc[i][2] + b2, acc[i][3] + b3);
    if (obuf == 5) {
      const float q0 = pos[(size_t)p * 3], q1 = pos[(size_t)p * 3 + 1], q2 = pos[(size_t)p * 3 + 2];
      r.x += wpx[0] * q0 + wpy[0] * q1 + wpz[0] * q2 + bpv[0];
      r.y += wpx[1] * q0 + wpy[1] * q1 + wpz[1] * q2 + bpv[1];
      r.z += wpx[2] * q0 + wpy[2] * q1 + wpz[2] * q2 + bpv[2];
      r.w += wpx[3] * q0 + wpy[3] * q1 + wpz[3] * q2 + bpv[3];
    }
    *(float4*)&outp[(size_t)p * DIM + oloc + tx * 4] = r;
  }
}

// ---------------------------------------------------------------------------
// Attention. QK: all 64 lanes (lane = k + 32*dhalf), one shfl_xor(32) combine.
// ---------------------------------------------------------------------------
template <int DIM>
__global__ __launch_bounds__(256) void attn_kernel(
    const float* __restrict__ Uq, const float* __restrict__ Uk, const float* __restrict__ Uv,
    const float* __restrict__ Uqc, const float* __restrict__ Ukc, const float* __restrict__ W6g,
    const int* __restrict__ idxg, float* __restrict__ outF) {
  const int w = threadIdx.x >> 6, lane = threadIdx.x & 63;
  const int pt = blockIdx.x * 4 + w;
  const int b = pt >> 11;
  __shared__ int sidx[4][KNN];
  __shared__ float sqc[4][DIM], skc[4][DIM], sw6[4][DIM];
  __shared__ float sattn[4][KNN];
  const size_t rowo = (size_t)pt * DIM;
  if (lane < KNN) sidx[w][lane] = idxg[(size_t)pt * KNN + lane];
  for (int d = lane; d < DIM; d += 64) {
    sqc[w][d] = Uqc[rowo + d];
    skc[w][d] = Ukc[rowo + d];
    sw6[w][d] = W6g[rowo + d];
  }
  __syncthreads();
  {
    const int kk = lane & 31;
    const int h = lane >> 5;
    const int ik = sidx[w][kk];
    const float* qr = Uq + (size_t)(b * NP + ik) * DIM;
    const float* kr = Uk + (size_t)(b * NP + ik) * DIM;
    float lg = 0.f;
    const int d0 = h * (DIM / 2), d1 = d0 + DIM / 2;
    for (int d = d0; d < d1; d += 4) {
      float4 qa = *(const float4*)(qr + d);
      float4 ka = *(const float4*)(kr + d);
      float4 qc = *(const float4*)(&sqc[w][d]);
      float4 kc = *(const float4*)(&skc[w][d]);
      lg += (qa.x + qc.x) * (ka.x + kc.x);
      lg += (qa.y + qc.y) * (ka.y + kc.y);
      lg += (qa.z + qc.z) * (ka.z + kc.z);
      lg += (qa.w + qc.w) * (ka.w + kc.w);
    }
    lg += __shfl_xor(lg, 32);
    lg *= (DIM == 64) ? 0.125f : 0.08838834764831845f;  // 1/sqrt(DIM)
    float m = lg;
#pragma unroll
    for (int off = 16; off; off >>= 1) m = fmaxf(m, __shfl_xor(m, off));
    float e = expf(lg - m);
    float s = e;
#pragma unroll
    for (int off = 16; off; off >>= 1) s += __shfl_xor(s, off);
    if (lane < KNN) sattn[w][lane] = e / s;
  }
  __syncthreads();
  float acc[DIM / 64];
#pragma unroll
  for (int q = 0; q < DIM / 64; ++q) acc[q] = 0.f;
  for (int k = 0; k < KNN; ++k) {
    const int ik = sidx[w][k];
    const float a = sattn[w][k];
    const float* vr = Uv + (size_t)(b * NP + ik) * DIM;
#pragma unroll
    for (int q = 0; q < DIM / 64; ++q) {
      const int d = q * 64 + lane;
      acc[q] = fmaf(a, vr[d] + sw6[w][d], acc[q]);
    }
  }
#pragma unroll
  for (int q = 0; q < DIM / 64; ++q) outF[rowo + q * 64 + lane] = acc[q];
}

// ---------------------------------------------------------------------------
// Pooling, two stages for HBM parallelism.
// ---------------------------------------------------------------------------
#define PCHUNKS 16
__global__ __launch_bounds__(256) void pool1_kernel(const float* __restrict__ x1,
                                                    const float* __restrict__ x2,
                                                    const float* __restrict__ x3,
                                                    float* __restrict__ pmax,
                                                    float* __restrict__ psum) {
  const int b = blockIdx.x, ch = blockIdx.y, c = threadIdx.x;
  const float* src;
  int dim, cl;
  if (c < 64) {
    src = x1 + (size_t)b * NP * 64; dim = 64; cl = c;
  } else if (c < 128) {
    src = x2 + (size_t)b * NP * 64; dim = 64; cl = c - 64;
  } else {
    src = x3 + (size_t)b * NP * 128; dim = 128; cl = c - 128;
  }
  const int n0 = ch * (NP / PCHUNKS), n1 = n0 + NP / PCHUNKS;
  float mx = NEG_INF, sm = 0.f;
#pragma unroll 8
  for (int n = n0; n < n1; ++n) {
    float v = src[(size_t)n * dim + cl];
    mx = fmaxf(mx, v);
    sm += v;
  }
  const size_t o = ((size_t)b * PCHUNKS + ch) * 256 + c;
  pmax[o] = mx;
  psum[o] = sm;
}

__global__ __launch_bounds__(256) void pool2_kernel(const float* __restrict__ pmax,
                                                    const float* __restrict__ psum,
                                                    float* __restrict__ out) {
  const int b = blockIdx.x, c = threadIdx.x;
  float mx = NEG_INF, sm = 0.f;
#pragma unroll
  for (int ch = 0; ch < PCHUNKS; ++ch) {
    const size_t o = ((size_t)b * PCHUNKS + ch) * 256 + c;
    mx = fmaxf(mx, pmax[o]);
    sm += psum[o];
  }
  out[b * 512 + c] = mx;
  out[b * 512 + 256 + c] = sm * (1.0f / 2048.0f);
}

// ---------------------------------------------------------------------------
extern "C" void kernel_launch(void* const* d_in, const int* in_sizes, int n_in,
                              void* d_out, int out_size, void* d_ws, size_t ws_size,
                              hipStream_t stream) {
  const float* x = (const float*)d_in[0];
  const float* W[24];
  for (int i = 0; i < 24; ++i) W[i] = (const float*)d_in[1 + i];

  float* ws = (float*)d_ws;
  size_t off = 0;
  float* partial = ws + off; off += (size_t)NB * NP * 3;
  int* idxb = (int*)(ws + off); off += (size_t)TOTPTS * KNN;
  float* x1 = ws + off; off += (size_t)TOTPTS * 64;
  float* x2 = ws + off; off += (size_t)TOTPTS * 64;
  float* x3 = ws + off; off += (size_t)TOTPTS * 128;
  float* Uq = ws + off;  off += (size_t)TOTPTS * 128;
  float* Uk = ws + off;  off += (size_t)TOTPTS * 128;
  float* Uv = ws + off;  off += (size_t)TOTPTS * 128;
  float* Uqc = ws + off; off += (size_t)TOTPTS * 128;
  float* Ukc = ws + off; off += (size_t)TOTPTS * 128;
  float* W6 = ws + off;  off += (size_t)TOTPTS * 128;
  float* Wcat = ws + off; off += (size_t)64 * 768;
  float* bcat = ws + off; off += 768;
  float* pmax = ws + off; off += (size_t)NB * PCHUNKS * 256;
  float* psum = ws + off; off += (size_t)NB * PCHUNKS * 256;
  if (ws_size < off * sizeof(float)) return;

  fps_kernel<<<NB, 1024, 0, stream>>>(x, partial);

  // -------- layer 1 (C=3, DIM=64): fused kNN
  knn3_kernel<<<dim3(NP / 16, 1, NB), 1024, 0, stream>>>(partial, idxb);
  proj_kernel<3, 64><<<TOTPTS / 16, 256, 0, stream>>>(
      partial, partial, W[0], W[1], W[2], W[3], W[4], W[5], W[6], W[7],
      Uq, Uk, Uv, Uqc, Ukc, W6);
  attn_kernel<64><<<TOTPTS / 4, 256, 0, stream>>>(Uq, Uk, Uv, Uqc, Ukc, W6, idxb, x1);

  // -------- layer 2 (C=64, DIM=64): fused kNN (no D matrix)
  knn64_kernel<<<dim3(NP / 8, 1, NB), 512, 0, stream>>>(x1, idxb);
  prep_kernel<64><<<2, 256, 0, stream>>>(W[8], W[9], W[10], W[11], W[12], W[13], Wcat, bcat);
  gemm_proj<64><<<dim3(TOTPTS / 64, 6), 256, 0, stream>>>(
      x1, Wcat, bcat, partial, W[14], W[15], Uq, Uqc, Uk, Ukc, Uv, W6);
  attn_kernel<64><<<TOTPTS / 4, 256, 0, stream>>>(Uq, Uk, Uv, Uqc, Ukc, W6, idxb, x2);

  // -------- layer 3 (C=64, DIM=128): fused kNN
  knn64_kernel<<<dim3(NP / 8, 1, NB), 512, 0, stream>>>(x2, idxb);
  prep_kernel<128><<<3, 256, 0, stream>>>(W[16], W[17], W[18], W[19], W[20], W[21], Wcat, bcat);
  gemm_proj<128><<<dim3(TOTPTS / 64, 12), 256, 0, stream>>>(
      x2, Wcat, bcat, partial, W[22], W[23], Uq, Uqc, Uk, Ukc, Uv, W6);
  attn_kernel<128><<<TOTPTS / 4, 256, 0, stream>>>(Uq, Uk, Uv, Uqc, Ukc, W6, idxb, x3);

  pool1_kernel<<<dim3(NB, PCHUNKS), 256, 0, stream>>>(x1, x2, x3, pmax, psum);
  pool2_kernel<<<NB, 256, 0, stream>>>(pmax, psum, (float*)d_out);
}

// Round 16
// 4459.696 us; speedup vs baseline: 1.0976x; 1.0286x over previous
//
#include <hip/hip_runtime.h>
#include <math.h>

#define NB 8
#define NIN 16384
#define NP 2048
#define KNN 32
#define TOTPTS (NB * NP)   // 16384

#define NEG_INF (-__builtin_inff())
#define POS_INF (__builtin_inff())

// ---------------------------------------------------------------------------
// Packed fp32 ops (VOP3P): 2 round-to-nearest f32 ops per instruction.
// Bit-exact to __fadd_rn / __fmul_rn on each half.
// ---------------------------------------------------------------------------
__device__ __forceinline__ float2 pk_add(float2 a, float2 b) {
  float2 d;
  asm("v_pk_add_f32 %0, %1, %2" : "=v"(d) : "v"(a), "v"(b));
  return d;
}
__device__ __forceinline__ float2 pk_mul(float2 a, float2 b) {
  float2 d;
  asm("v_pk_mul_f32 %0, %1, %2" : "=v"(d) : "v"(a), "v"(b));
  return d;
}

// ---------------------------------------------------------------------------
// DPP wave64 reductions; result valid in lane 63.
// ---------------------------------------------------------------------------
#define DPP_F(old, v, C, RM) \
  __int_as_float(__builtin_amdgcn_update_dpp(__float_as_int(old), __float_as_int(v), C, RM, 0xf, false))
#define DPP_I(old, v, C, RM) \
  __builtin_amdgcn_update_dpp(old, v, C, RM, 0xf, false)

__device__ __forceinline__ float wave_max_f(float v) {
  v = fmaxf(v, DPP_F(NEG_INF, v, 0x111, 0xf));
  v = fmaxf(v, DPP_F(NEG_INF, v, 0x112, 0xf));
  v = fmaxf(v, DPP_F(NEG_INF, v, 0x114, 0xf));
  v = fmaxf(v, DPP_F(NEG_INF, v, 0x118, 0xf));
  v = fmaxf(v, DPP_F(NEG_INF, v, 0x142, 0xa));
  v = fmaxf(v, DPP_F(NEG_INF, v, 0x143, 0xc));
  return v;
}
__device__ __forceinline__ int wave_min_i(int v) {
  v = min(v, DPP_I(0x7fffffff, v, 0x111, 0xf));
  v = min(v, DPP_I(0x7fffffff, v, 0x112, 0xf));
  v = min(v, DPP_I(0x7fffffff, v, 0x114, 0xf));
  v = min(v, DPP_I(0x7fffffff, v, 0x118, 0xf));
  v = min(v, DPP_I(0x7fffffff, v, 0x142, 0xa));
  v = min(v, DPP_I(0x7fffffff, v, 0x143, 0xc));
  return v;
}

__device__ __forceinline__ float readlane63f(float v) {
  return __int_as_float(__builtin_amdgcn_readlane(__float_as_int(v), 63));
}

// ---------------------------------------------------------------------------
// FPS: exact r9 structure (best measured: ~3430 us across r9/r13/r14/r15).
// ---------------------------------------------------------------------------
__global__ __launch_bounds__(1024) void fps_kernel(const float* __restrict__ x,
                                                   float* __restrict__ partial) {
  const int b = blockIdx.x;
  const int t = threadIdx.x;
  const int w = t >> 6, l = t & 63;
  const float* xb = x + (size_t)b * NIN * 3;
  float* pb = partial + (size_t)b * NP * 3;
  __shared__ unsigned long long skey[NP][2];
  __shared__ float4 swave[2][16];
  for (int i = t; i < NP; i += 1024) { skey[i][0] = 0ull; skey[i][1] = 0ull; }

  float2 px[8], py[8], pz[8], dd[8];
#pragma unroll
  for (int j = 0; j < 8; ++j) {
    const int i0 = (2 * j) * 1024 + t, i1 = (2 * j + 1) * 1024 + t;
    px[j] = make_float2(xb[3 * i0], xb[3 * i1]);
    py[j] = make_float2(xb[3 * i0 + 1], xb[3 * i1 + 1]);
    pz[j] = make_float2(xb[3 * i0 + 2], xb[3 * i1 + 2]);
  }
  const float qx0 = xb[0], qy0 = xb[1], qz0 = xb[2];
  if (t == 0) { pb[0] = qx0; pb[1] = qy0; pb[2] = qz0; }

  float bv = NEG_INF;
  int bi = 0;
  {
    const float2 nx2 = make_float2(-qx0, -qx0);
    const float2 ny2 = make_float2(-qy0, -qy0);
    const float2 nz2 = make_float2(-qz0, -qz0);
#pragma unroll
    for (int j = 0; j < 8; ++j) {
      float2 dx = pk_add(px[j], nx2), dy = pk_add(py[j], ny2), dz = pk_add(pz[j], nz2);
      float2 nd = pk_add(pk_add(pk_mul(dx, dx), pk_mul(dy, dy)), pk_mul(dz, dz));
      dd[j] = nd;
      if (nd.x > bv) { bv = nd.x; bi = (2 * j) * 1024 + t; }
      if (nd.y > bv) { bv = nd.y; bi = (2 * j + 1) * 1024 + t; }
    }
  }

  {
    const float wm = wave_max_f(bv);
    const float smaxw = readlane63f(wm);
    const int sel = (bv == smaxw) ? bi : 0x7fffffff;
    const int wiw = __builtin_amdgcn_readlane(wave_min_i(sel), 63);
    const float ax = xb[3 * wiw], ay = xb[3 * wiw + 1], az = xb[3 * wiw + 2];
    if (l == 63) {
      const unsigned long long key =
          ((unsigned long long)__float_as_uint(smaxw) << 32) | (unsigned int)(~wiw);
      atomicMax(&skey[1][w & 1], key);
    }
    if (l == 0) swave[1][w] = make_float4(ax, ay, az, 0.f);
  }
  __syncthreads();

  for (int it = 1; it < NP; ++it) {
    const unsigned long long k0 = skey[it][0], k1 = skey[it][1];
    const unsigned long long gk = (k0 > k1) ? k0 : k1;
    const int gbi = (int)(~(unsigned int)gk);
    const int wstar = (gbi >> 6) & 15;
    const float4 qc = swave[it & 1][wstar];
    const float nqx = qc.x, nqy = qc.y, nqz = qc.z;
    if (t == 0) { pb[3 * it] = nqx; pb[3 * it + 1] = nqy; pb[3 * it + 2] = nqz; }

    const float2 nx2 = make_float2(-nqx, -nqx);
    const float2 ny2 = make_float2(-nqy, -nqy);
    const float2 nz2 = make_float2(-nqz, -nqz);
    bv = NEG_INF;
    bi = 0;
#pragma unroll
    for (int j = 0; j < 8; ++j) {
      float2 dx = pk_add(px[j], nx2), dy = pk_add(py[j], ny2), dz = pk_add(pz[j], nz2);
      float2 nd = pk_add(pk_add(pk_mul(dx, dx), pk_mul(dy, dy)), pk_mul(dz, dz));
      const float a0 = fminf(dd[j].x, nd.x);
      dd[j].x = a0;
      if (a0 > bv) { bv = a0; bi = (2 * j) * 1024 + t; }
      const float a1 = fminf(dd[j].y, nd.y);
      dd[j].y = a1;
      if (a1 > bv) { bv = a1; bi = (2 * j + 1) * 1024 + t; }
    }

    if (it + 1 < NP) {
      const float wm = wave_max_f(bv);
      const float smaxw = readlane63f(wm);
      const int sel = (bv == smaxw) ? bi : 0x7fffffff;
      const int wiw = __builtin_amdgcn_readlane(wave_min_i(sel), 63);
      const float ax = xb[3 * wiw], ay = xb[3 * wiw + 1], az = xb[3 * wiw + 2];
      if (l == 63) {
        const unsigned long long key =
            ((unsigned long long)__float_as_uint(smaxw) << 32) | (unsigned int)(~wiw);
        atomicMax(&skey[it + 1][w & 1], key);
      }
      if (l == 0) swave[(it + 1) & 1][w] = make_float4(ax, ay, az, 0.f);
    }
    __syncthreads();
  }
}

// ---------------------------------------------------------------------------
// xx[i] = sum_c F[i][c]^2  (rn, ascending c)
// ---------------------------------------------------------------------------
__global__ void xx_kernel(const float* __restrict__ F, float* __restrict__ xxg, int C) {
  int i = blockIdx.x * 256 + threadIdx.x;
  if (i >= TOTPTS) return;
  const float* f = F + (size_t)i * C;
  float s = 0.f;
  for (int c = 0; c < C; ++c) s = __fadd_rn(s, __fmul_rn(f[c], f[c]));
  xxg[i] = s;
}

// ---------------------------------------------------------------------------
// Fused layer-1 kNN (C=3): arithmetic bit-identical to dist_gemm<3>+select.
// ---------------------------------------------------------------------------
__global__ __launch_bounds__(1024) void knn3_kernel(const float* __restrict__ F,
                                                    int* __restrict__ idxg) {
  const int b = blockIdx.z;
  const int t = threadIdx.x;
  const int w = t >> 6, lane = t & 63;
  __shared__ float spx[NP], spy[NP], spz[NP], sxx[NP];
  const float* Fb = F + (size_t)b * NP * 3;
  for (int i = t; i < NP; i += 1024) {
    const float a0 = Fb[3 * i], a1 = Fb[3 * i + 1], a2 = Fb[3 * i + 2];
    spx[i] = a0; spy[i] = a1; spz[i] = a2;
    float s = __fadd_rn(0.f, __fmul_rn(a0, a0));
    s = __fadd_rn(s, __fmul_rn(a1, a1));
    s = __fadd_rn(s, __fmul_rn(a2, a2));
    sxx[i] = s;
  }
  __syncthreads();
  const int row = blockIdx.x * 16 + w;
  const float a0 = spx[row], a1 = spy[row], a2 = spz[row];
  const float xn = sxx[row];
  float v[32];
#pragma unroll
  for (int s = 0; s < 32; ++s) {
    const int m = s * 64 + lane;
    float acc = fmaf(a0, spx[m], 0.f);
    acc = fmaf(a1, spy[m], acc);
    acc = fmaf(a2, spz[m], acc);
    v[s] = __fsub_rn(__fsub_rn(2.0f * acc, xn), sxx[m]);
  }
  int* out = idxg + ((size_t)b * NP + row) * KNN;
  for (int tt = 0; tt < KNN; ++tt) {
    float bv = v[0];
    int bs = 0;
#pragma unroll
    for (int s = 1; s < 32; ++s) {
      if (v[s] > bv) { bv = v[s]; bs = s; }
    }
    int bi = bs * 64 + lane;
    const float vmax = readlane63f(wave_max_f(bv));
    const int sel = (bv == vmax) ? bi : 0x7fffffff;
    const int wbi = __builtin_amdgcn_readlane(wave_min_i(sel), 63);
    if (lane == 0) out[tt] = wbi;
    const bool own = (lane == (wbi & 63));
    const int cs = wbi >> 6;
#pragma unroll
    for (int s = 0; s < 32; ++s)
      if (own && s == cs) v[s] = NEG_INF;
  }
}

// ---------------------------------------------------------------------------
// D[n][m] = (2*<f_n,f_m> - xx[n]) - xx[m]   (neg squared dist), C=64.
// ---------------------------------------------------------------------------
template <int C>
__global__ __launch_bounds__(256) void dist_gemm(const float* __restrict__ F,
                                                 const float* __restrict__ xxg,
                                                 float* __restrict__ D, int bofs) {
  __shared__ float As[64][C + 1];
  __shared__ float Bs[64][C + 1];
  const int b = bofs + blockIdx.z;
  float* Ds = D + (size_t)blockIdx.z * NP * NP;
  const int tid = threadIdx.x;
  const int n0 = blockIdx.y * 64, m0 = blockIdx.x * 64;
  const float* Fb = F + (size_t)b * NP * C;
  const float* xxb = xxg + b * NP;
  for (int t = tid; t < 64 * C; t += 256) {
    int r = t / C, c = t - r * C;
    As[r][c] = Fb[(size_t)(n0 + r) * C + c];
    Bs[r][c] = Fb[(size_t)(m0 + r) * C + c];
  }
  __syncthreads();
  const int tx = tid & 15, ty = tid >> 4;
  float acc[4][4] = {};
  for (int c = 0; c < C; ++c) {
    float a[4], bb[4];
#pragma unroll
    for (int i = 0; i < 4; ++i) a[i] = As[ty * 4 + i][c];
#pragma unroll
    for (int j = 0; j < 4; ++j) bb[j] = Bs[tx * 4 + j][c];
#pragma unroll
    for (int i = 0; i < 4; ++i)
#pragma unroll
      for (int j = 0; j < 4; ++j) acc[i][j] = fmaf(a[i], bb[j], acc[i][j]);
  }
#pragma unroll
  for (int i = 0; i < 4; ++i) {
    int n = n0 + ty * 4 + i;
    float xn = xxb[n];
    float4 o;
    o.x = __fsub_rn(__fsub_rn(2.0f * acc[i][0], xn), xxb[m0 + tx * 4 + 0]);
    o.y = __fsub_rn(__fsub_rn(2.0f * acc[i][1], xn), xxb[m0 + tx * 4 + 1]);
    o.z = __fsub_rn(__fsub_rn(2.0f * acc[i][2], xn), xxb[m0 + tx * 4 + 2]);
    o.w = __fsub_rn(__fsub_rn(2.0f * acc[i][3], xn), xxb[m0 + tx * 4 + 3]);
    *(float4*)&Ds[(size_t)n * NP + m0 + tx * 4] = o;
  }
}

// ---------------------------------------------------------------------------
// top-32 (value desc, ties -> lower index) per row; one wave per row.
// ---------------------------------------------------------------------------
__global__ __launch_bounds__(256) void select_kernel(const float* __restrict__ D,
                                                     int* __restrict__ idxg, int bofs) {
  const int lane = threadIdx.x & 63;
  const int b = bofs + blockIdx.z;
  const int row = blockIdx.x * 4 + (threadIdx.x >> 6);
  const float* Drow = D + (size_t)blockIdx.z * NP * NP + (size_t)row * NP;
  float v[32];
#pragma unroll
  for (int s = 0; s < 32; ++s) v[s] = Drow[s * 64 + lane];
  int* out = idxg + ((size_t)b * NP + row) * KNN;
  for (int t = 0; t < KNN; ++t) {
    float bv = v[0];
    int bs = 0;
#pragma unroll
    for (int s = 1; s < 32; ++s) {
      if (v[s] > bv) { bv = v[s]; bs = s; }
    }
    int bi = bs * 64 + lane;
    const float vmax = readlane63f(wave_max_f(bv));
    const int sel = (bv == vmax) ? bi : 0x7fffffff;
    const int wbi = __builtin_amdgcn_readlane(wave_min_i(sel), 63);
    if (lane == 0) out[t] = wbi;
    const bool own = (lane == (wbi & 63));
    const int cs = wbi >> 6;
#pragma unroll
    for (int s = 0; s < 32; ++s)
      if (own && s == cs) v[s] = NEG_INF;
  }
}

// ---------------------------------------------------------------------------
// Layer-1 projections (C=3): per-point gather form (cheap at K=3).
// ---------------------------------------------------------------------------
template <int C, int DIM>
__global__ __launch_bounds__(256) void proj_kernel(
    const float* __restrict__ F, const float* __restrict__ pos,
    const float* __restrict__ Wq, const float* __restrict__ bq,
    const float* __restrict__ Wk, const float* __restrict__ bk,
    const float* __restrict__ Wv, const float* __restrict__ bv,
    const float* __restrict__ Wp, const float* __restrict__ bp,
    float* __restrict__ Uq, float* __restrict__ Uk, float* __restrict__ Uv,
    float* __restrict__ Uqc, float* __restrict__ Ukc, float* __restrict__ W6) {
  constexpr int PTS = 16;
  constexpr int GROUPS = 256 / DIM;
  constexpr int PPT = PTS / GROUPS;
  __shared__ float xs[PTS][C];
  __shared__ float ps[PTS][3];
  const int tid = threadIdx.x;
  const int base = blockIdx.x * PTS;
  for (int t = tid; t < PTS * C; t += 256) {
    int r = t / C;
    xs[r][t - r * C] = F[(size_t)(base + r) * C + (t - r * C)];
  }
  for (int t = tid; t < PTS * 3; t += 256) {
    int r = t / 3;
    ps[r][t - r * 3] = pos[(size_t)(base + r) * 3 + (t - r * 3)];
  }
  __syncthreads();
  const int g = tid / DIM;
  const int d = tid - g * DIM;
  float uq[PPT], uqd[PPT], uk[PPT], ukd[PPT], uv[PPT], uvd[PPT];
#pragma unroll
  for (int p = 0; p < PPT; ++p) { uq[p] = uqd[p] = uk[p] = ukd[p] = uv[p] = uvd[p] = 0.f; }
  const float* wqr = Wq + (size_t)d * (2 * C);
  const float* wkr = Wk + (size_t)d * (2 * C);
  const float* wvr = Wv + (size_t)d * (2 * C);
  for (int c = 0; c < C; ++c) {
    const float wq1 = wqr[c], wqd_ = wqr[C + c] - wq1;
    const float wk1 = wkr[c], wkd_ = wkr[C + c] - wk1;
    const float wv1 = wvr[c], wvd_ = wvr[C + c] - wv1;
#pragma unroll
    for (int p = 0; p < PPT; ++p) {
      const float xc = xs[g + p * GROUPS][c];
      uq[p] = fmaf(wq1, xc, uq[p]);
      uqd[p] = fmaf(wqd_, xc, uqd[p]);
      uk[p] = fmaf(wk1, xc, uk[p]);
      ukd[p] = fmaf(wkd_, xc, ukd[p]);
      uv[p] = fmaf(wv1, xc, uv[p]);
      uvd[p] = fmaf(wvd_, xc, uvd[p]);
    }
  }
  const float bqd = bq[d], bkd = bk[d], bvd = bv[d];
  const float wp0 = Wp[d * 3], wp1 = Wp[d * 3 + 1], wp2 = Wp[d * 3 + 2], bpd = bp[d];
#pragma unroll
  for (int p = 0; p < PPT; ++p) {
    const int lp = g + p * GROUPS;
    const size_t o = (size_t)(base + lp) * DIM + d;
    const float pd = wp0 * ps[lp][0] + wp1 * ps[lp][1] + wp2 * ps[lp][2] + bpd;
    Uq[o] = uq[p];
    Uqc[o] = uqd[p] + bqd;
    Uk[o] = uk[p];
    Ukc[o] = ukd[p] + bkd;
    Uv[o] = uv[p];
    W6[o] = uvd[p] + bvd + pd;
  }
}

// ---------------------------------------------------------------------------
// prep: Wcat[c][o] (c<64, o<6*DIM) = [Wq1|Wqd|Wk1|Wkd|Wv1|Wvd] transposed;
// bcat[o] = [0|bq|0|bk|0|bv].
// ---------------------------------------------------------------------------
template <int DIM>
__global__ void prep_kernel(const float* __restrict__ Wq, const float* __restrict__ bq,
                            const float* __restrict__ Wk, const float* __restrict__ bk,
                            const float* __restrict__ Wv, const float* __restrict__ bv,
                            float* __restrict__ Wcat, float* __restrict__ bcat) {
  const int o = blockIdx.x * 256 + threadIdx.x;
  constexpr int ND = 6 * DIM;
  if (o >= ND) return;
  const int blk = o / DIM, d = o % DIM;
  bcat[o] = (blk == 1) ? bq[d] : (blk == 3) ? bk[d] : (blk == 5) ? bv[d] : 0.f;
  const float* W = (blk < 2) ? Wq : (blk < 4) ? Wk : Wv;
  for (int c = 0; c < 64; ++c) {
    const float w1 = W[(size_t)d * 128 + c];
    const float w2 = W[(size_t)d * 128 + 64 + c];
    Wcat[(size_t)c * ND + o] = (blk & 1) ? (w2 - w1) : w1;
  }
}

// ---------------------------------------------------------------------------
// proj GEMM (layers 2/3, K=64): As[pt][k], Bs[k][col].
// pos-projection fused into the W6 (obuf==5) epilogue — no P buffer.
// ---------------------------------------------------------------------------
template <int DIM>
__global__ __launch_bounds__(256) void gemm_proj(
    const float* __restrict__ F, const float* __restrict__ Wcat,
    const float* __restrict__ bcat, const float* __restrict__ pos,
    const float* __restrict__ Wp, const float* __restrict__ bp,
    float* __restrict__ Uq, float* __restrict__ Uqc, float* __restrict__ Uk,
    float* __restrict__ Ukc, float* __restrict__ Uv, float* __restrict__ W6) {
  constexpr int ND = 6 * DIM;
  __shared__ float As[64][65];
  __shared__ float Bs[64][65];
  const int tid = threadIdx.x;
  const int r0blk = blockIdx.x * 64;
  const int n0 = blockIdx.y * 64;
  {
    const int r0 = tid >> 4, c4 = (tid & 15) * 4;
    for (int r = r0; r < 64; r += 16) {
      float4 a = *(const float4*)&F[(size_t)(r0blk + r) * 64 + c4];
      As[r][c4] = a.x; As[r][c4 + 1] = a.y; As[r][c4 + 2] = a.z; As[r][c4 + 3] = a.w;
      float4 bb = *(const float4*)&Wcat[(size_t)r * ND + n0 + c4];
      Bs[r][c4] = bb.x; Bs[r][c4 + 1] = bb.y; Bs[r][c4 + 2] = bb.z; Bs[r][c4 + 3] = bb.w;
    }
  }
  __syncthreads();
  const int tx = tid & 15, ty = tid >> 4;
  float acc[4][4] = {};
#pragma unroll 4
  for (int c = 0; c < 64; ++c) {
    float a[4], bb[4];
#pragma unroll
    for (int i = 0; i < 4; ++i) a[i] = As[ty * 4 + i][c];
#pragma unroll
    for (int j = 0; j < 4; ++j) bb[j] = Bs[c][tx * 4 + j];
#pragma unroll
    for (int i = 0; i < 4; ++i)
#pragma unroll
      for (int j = 0; j < 4; ++j) acc[i][j] = fmaf(a[i], bb[j], acc[i][j]);
  }
  const int obuf = n0 / DIM;
  const int oloc = n0 - obuf * DIM;
  float* outp = (obuf == 0) ? Uq : (obuf == 1) ? Uqc : (obuf == 2) ? Uk
              : (obuf == 3) ? Ukc : (obuf == 4) ? Uv : W6;
  const float b0 = bcat[n0 + tx * 4], b1 = bcat[n0 + tx * 4 + 1];
  const float b2 = bcat[n0 + tx * 4 + 2], b3 = bcat[n0 + tx * 4 + 3];
  float wpx[4], wpy[4], wpz[4], bpv[4];
  if (obuf == 5) {
#pragma unroll
    for (int j = 0; j < 4; ++j) {
      const int oc = oloc + tx * 4 + j;
      wpx[j] = Wp[oc * 3]; wpy[j] = Wp[oc * 3 + 1]; wpz[j] = Wp[oc * 3 + 2];
      bpv[j] = bp[oc];
    }
  }
#pragma unroll
  for (int i = 0; i < 4; ++i) {
    const int p = r0blk + ty * 4 + i;
    float4 r = make_float4(acc[i][0] + b0, acc[i][1] + b1, acc[i][2] + b2, acc[i][3] + b3);
    if (obuf == 5) {
      const float q0 = pos[(size_t)p * 3], q1 = pos[(size_t)p * 3 + 1], q2 = pos[(size_t)p * 3 + 2];
      r.x += wpx[0] * q0 + wpy[0] * q1 + wpz[0] * q2 + bpv[0];
      r.y += wpx[1] * q0 + wpy[1] * q1 + wpz[1] * q2 + bpv[1];
      r.z += wpx[2] * q0 + wpy[2] * q1 + wpz[2] * q2 + bpv[2];
      r.w += wpx[3] * q0 + wpy[3] * q1 + wpz[3] * q2 + bpv[3];
    }
    *(float4*)&outp[(size_t)p * DIM + oloc + tx * 4] = r;
  }
}

// ---------------------------------------------------------------------------
// Attention. QK: all 64 lanes (lane = k + 32*dhalf), one shfl_xor(32) combine.
// ---------------------------------------------------------------------------
template <int DIM>
__global__ __launch_bounds__(256) void attn_kernel(
    const float* __restrict__ Uq, const float* __restrict__ Uk, const float* __restrict__ Uv,
    const float* __restrict__ Uqc, const float* __restrict__ Ukc, const float* __restrict__ W6g,
    const int* __restrict__ idxg, float* __restrict__ outF) {
  const int w = threadIdx.x >> 6, lane = threadIdx.x & 63;
  const int pt = blockIdx.x * 4 + w;
  const int b = pt >> 11;
  __shared__ int sidx[4][KNN];
  __shared__ float sqc[4][DIM], skc[4][DIM], sw6[4][DIM];
  __shared__ float sattn[4][KNN];
  const size_t rowo = (size_t)pt * DIM;
  if (lane < KNN) sidx[w][lane] = idxg[(size_t)pt * KNN + lane];
  for (int d = lane; d < DIM; d += 64) {
    sqc[w][d] = Uqc[rowo + d];
    skc[w][d] = Ukc[rowo + d];
    sw6[w][d] = W6g[rowo + d];
  }
  __syncthreads();
  {
    const int kk = lane & 31;
    const int h = lane >> 5;
    const int ik = sidx[w][kk];
    const float* qr = Uq + (size_t)(b * NP + ik) * DIM;
    const float* kr = Uk + (size_t)(b * NP + ik) * DIM;
    float lg = 0.f;
    const int d0 = h * (DIM / 2), d1 = d0 + DIM / 2;
    for (int d = d0; d < d1; d += 4) {
      float4 qa = *(const float4*)(qr + d);
      float4 ka = *(const float4*)(kr + d);
      float4 qc = *(const float4*)(&sqc[w][d]);
      float4 kc = *(const float4*)(&skc[w][d]);
      lg += (qa.x + qc.x) * (ka.x + kc.x);
      lg += (qa.y + qc.y) * (ka.y + kc.y);
      lg += (qa.z + qc.z) * (ka.z + kc.z);
      lg += (qa.w + qc.w) * (ka.w + kc.w);
    }
    lg += __shfl_xor(lg, 32);
    lg *= (DIM == 64) ? 0.125f : 0.08838834764831845f;  // 1/sqrt(DIM)
    float m = lg;
#pragma unroll
    for (int off = 16; off; off >>= 1) m = fmaxf(m, __shfl_xor(m, off));
    float e = expf(lg - m);
    float s = e;
#pragma unroll
    for (int off = 16; off; off >>= 1) s += __shfl_xor(s, off);
    if (lane < KNN) sattn[w][lane] = e / s;
  }
  __syncthreads();
  float acc[DIM / 64];
#pragma unroll
  for (int q = 0; q < DIM / 64; ++q) acc[q] = 0.f;
  for (int k = 0; k < KNN; ++k) {
    const int ik = sidx[w][k];
    const float a = sattn[w][k];
    const float* vr = Uv + (size_t)(b * NP + ik) * DIM;
#pragma unroll
    for (int q = 0; q < DIM / 64; ++q) {
      const int d = q * 64 + lane;
      acc[q] = fmaf(a, vr[d] + sw6[w][d], acc[q]);
    }
  }
#pragma unroll
  for (int q = 0; q < DIM / 64; ++q) outF[rowo + q * 64 + lane] = acc[q];
}

// ---------------------------------------------------------------------------
// Pooling, two stages for HBM parallelism.
// ---------------------------------------------------------------------------
#define PCHUNKS 16
__global__ __launch_bounds__(256) void pool1_kernel(const float* __restrict__ x1,
                                                    const float* __restrict__ x2,
                                                    const float* __restrict__ x3,
                                                    float* __restrict__ pmax,
                                                    float* __restrict__ psum) {
  const int b = blockIdx.x, ch = blockIdx.y, c = threadIdx.x;
  const float* src;
  int dim, cl;
  if (c < 64) {
    src = x1 + (size_t)b * NP * 64; dim = 64; cl = c;
  } else if (c < 128) {
    src = x2 + (size_t)b * NP * 64; dim = 64; cl = c - 64;
  } else {
    src = x3 + (size_t)b * NP * 128; dim = 128; cl = c - 128;
  }
  const int n0 = ch * (NP / PCHUNKS), n1 = n0 + NP / PCHUNKS;
  float mx = NEG_INF, sm = 0.f;
#pragma unroll 8
  for (int n = n0; n < n1; ++n) {
    float v = src[(size_t)n * dim + cl];
    mx = fmaxf(mx, v);
    sm += v;
  }
  const size_t o = ((size_t)b * PCHUNKS + ch) * 256 + c;
  pmax[o] = mx;
  psum[o] = sm;
}

__global__ __launch_bounds__(256) void pool2_kernel(const float* __restrict__ pmax,
                                                    const float* __restrict__ psum,
                                                    float* __restrict__ out) {
  const int b = blockIdx.x, c = threadIdx.x;
  float mx = NEG_INF, sm = 0.f;
#pragma unroll
  for (int ch = 0; ch < PCHUNKS; ++ch) {
    const size_t o = ((size_t)b * PCHUNKS + ch) * 256 + c;
    mx = fmaxf(mx, pmax[o]);
    sm += psum[o];
  }
  out[b * 512 + c] = mx;
  out[b * 512 + 256 + c] = sm * (1.0f / 2048.0f);
}

// ---------------------------------------------------------------------------
extern "C" void kernel_launch(void* const* d_in, const int* in_sizes, int n_in,
                              void* d_out, int out_size, void* d_ws, size_t ws_size,
                              hipStream_t stream) {
  const float* x = (const float*)d_in[0];
  const float* W[24];
  for (int i = 0; i < 24; ++i) W[i] = (const float*)d_in[1 + i];

  float* ws = (float*)d_ws;
  size_t off = 0;
  float* partial = ws + off; off += (size_t)NB * NP * 3;
  float* xxbuf = ws + off;   off += TOTPTS;
  int* idxb = (int*)(ws + off); off += (size_t)TOTPTS * KNN;
  float* x1 = ws + off; off += (size_t)TOTPTS * 64;
  float* x2 = ws + off; off += (size_t)TOTPTS * 64;
  float* x3 = ws + off; off += (size_t)TOTPTS * 128;
  float* Uq = ws + off;  off += (size_t)TOTPTS * 128;
  float* Uk = ws + off;  off += (size_t)TOTPTS * 128;
  float* Uv = ws + off;  off += (size_t)TOTPTS * 128;
  float* Uqc = ws + off; off += (size_t)TOTPTS * 128;
  float* Ukc = ws + off; off += (size_t)TOTPTS * 128;
  float* W6 = ws + off;  off += (size_t)TOTPTS * 128;
  float* Wcat = ws + off; off += (size_t)64 * 768;
  float* bcat = ws + off; off += 768;
  float* pmax = ws + off; off += (size_t)NB * PCHUNKS * 256;
  float* psum = ws + off; off += (size_t)NB * PCHUNKS * 256;
  if (ws_size < off * sizeof(float)) return;

  float* Dbig = ws + off;
  const size_t need_big = (off + (size_t)NB * NP * NP) * sizeof(float);
  const bool bigws = (ws_size >= need_big);
  float* D = bigws ? Dbig : Uq;  // fallback: D aliases Uq..Uk region (16 MB)
  const int NZ = bigws ? NB : 1;

  fps_kernel<<<NB, 1024, 0, stream>>>(x, partial);

  // -------- layer 1 (C=3, DIM=64): fused kNN
  knn3_kernel<<<dim3(NP / 16, 1, NB), 1024, 0, stream>>>(partial, idxb);
  proj_kernel<3, 64><<<TOTPTS / 16, 256, 0, stream>>>(
      partial, partial, W[0], W[1], W[2], W[3], W[4], W[5], W[6], W[7],
      Uq, Uk, Uv, Uqc, Ukc, W6);
  attn_kernel<64><<<TOTPTS / 4, 256, 0, stream>>>(Uq, Uk, Uv, Uqc, Ukc, W6, idxb, x1);

  // -------- layer 2 (C=64, DIM=64)
  xx_kernel<<<TOTPTS / 256, 256, 0, stream>>>(x1, xxbuf, 64);
  for (int b = 0; b < NB; b += NZ) {
    dist_gemm<64><<<dim3(32, 32, NZ), 256, 0, stream>>>(x1, xxbuf, D, b);
    select_kernel<<<dim3(NP / 4, 1, NZ), 256, 0, stream>>>(D, idxb, b);
  }
  prep_kernel<64><<<2, 256, 0, stream>>>(W[8], W[9], W[10], W[11], W[12], W[13], Wcat, bcat);
  gemm_proj<64><<<dim3(TOTPTS / 64, 6), 256, 0, stream>>>(
      x1, Wcat, bcat, partial, W[14], W[15], Uq, Uqc, Uk, Ukc, Uv, W6);
  attn_kernel<64><<<TOTPTS / 4, 256, 0, stream>>>(Uq, Uk, Uv, Uqc, Ukc, W6, idxb, x2);

  // -------- layer 3 (C=64, DIM=128)
  xx_kernel<<<TOTPTS / 256, 256, 0, stream>>>(x2, xxbuf, 64);
  for (int b = 0; b < NB; b += NZ) {
    dist_gemm<64><<<dim3(32, 32, NZ), 256, 0, stream>>>(x2, xxbuf, D, b);
    select_kernel<<<dim3(NP / 4, 1, NZ), 256, 0, stream>>>(D, idxb, b);
  }
  prep_kernel<128><<<3, 256, 0, stream>>>(W[16], W[17], W[18], W[19], W[20], W[21], Wcat, bcat);
  gemm_proj<128><<<dim3(TOTPTS / 64, 12), 256, 0, stream>>>(
      x2, Wcat, bcat, partial, W[22], W[23], Uq, Uqc, Uk, Ukc, Uv, W6);
  attn_kernel<128><<<TOTPTS / 4, 256, 0, stream>>>(Uq, Uk, Uv, Uqc, Ukc, W6, idxb, x3);

  pool1_kernel<<<dim3(NB, PCHUNKS), 256, 0, stream>>>(x1, x2, x3, pmax, psum);
  pool2_kernel<<<NB, 256, 0, stream>>>(pmax, psum, (float*)d_out);
}